// Round 1
// baseline (454883.789 us; speedup 1.0000x reference)
//
#include <hip/hip_runtime.h>
#include <math.h>
#include <stdint.h>

#define T_STEPS 2048
#define XDIM 118
#define EMBD 128
#define HD 1536
#define NA 96
#define NB 128
#define NBLK (NA + NB + 1)

struct Params {
  const float *x, *h0in, *c0in;
  const float *Wih0, *Whh0, *bih0, *bhh0;
  const float *Wih1, *Whh1, *bih1, *bhh1;
  const float *Whl, *bhl, *Wout, *bout, *Wmap, *bmap;
  float *PRE, *Wc, *bc, *h0buf, *h1buf, *embbuf, *PART;
  uint32_t *cnt;   // cnt[0]=h0, cnt[32]=h1, cnt[64]=emb (separate cache lines)
  float *out;
};

__device__ __forceinline__ float bf_lo(uint32_t u){ return __uint_as_float(u << 16); }
__device__ __forceinline__ float bf_hi(uint32_t u){ return __uint_as_float(u & 0xffff0000u); }
__device__ __forceinline__ uint32_t packbf(float a, float b){
  uint32_t ua = __float_as_uint(a), ub = __float_as_uint(b);
  ua = (ua + 0x7fffu + ((ua >> 16) & 1u)) >> 16;           // RNE to bf16 (low half)
  ub = (ub + 0x7fffu + ((ub >> 16) & 1u)) & 0xffff0000u;   // RNE to bf16 (high half)
  return (ua & 0xffffu) | ub;
}
__device__ __forceinline__ float gload(const float* p){
  return __hip_atomic_load(p, __ATOMIC_RELAXED, __HIP_MEMORY_SCOPE_AGENT);
}
__device__ __forceinline__ void gstore(float* p, float v){
  __hip_atomic_store(p, v, __ATOMIC_RELAXED, __HIP_MEMORY_SCOPE_AGENT);
}
__device__ __forceinline__ int waitge(uint32_t* p, uint32_t tgt){
  uint32_t n = 0;
  while (__hip_atomic_load(p, __ATOMIC_ACQUIRE, __HIP_MEMORY_SCOPE_AGENT) < tgt){
    if (++n > 20000000u) return 0;   // bail out instead of hanging the harness
  }
  return 1;
}
__device__ __forceinline__ float sigm(float x){ return 1.f / (1.f + __expf(-x)); }

// ---------------- group A: LSTM layer 0 (96 blocks, 16 outputs each) ----------------
// wave w owns all 4 gates of output O = bid*16+w; lane l owns k-chunk [26l, 26l+26)
// K = 1664 = 1536 (h0 prev) ++ 128 (emb prev)
__device__ __forceinline__ float asrc(const Params& P, int r, int k){
  if (k < HD) return P.Whh0[(size_t)r * HD + k];
  return P.Wih0[(size_t)r * (XDIM + EMBD) + XDIM + (k - HD)];
}
__device__ void run_A(const Params& P, int bid){
  const int tid = threadIdx.x;
  const int w = tid >> 6, l = tid & 63;
  const int O = bid * 16 + w;
  __shared__ float xv[1664];
  __shared__ int sdead;
  if (tid == 0) sdead = 0;
  uint32_t wr[4][13];
#pragma unroll
  for (int g = 0; g < 4; ++g){
    int r = g * HD + O;
#pragma unroll
    for (int p = 0; p < 13; ++p){
      int k0 = l * 26 + 2 * p;
      wr[g][p] = packbf(asrc(P, r, k0), asrc(P, r, k0 + 1));
    }
  }
  float cst = P.c0in[O];
  __syncthreads();
  for (int t = 0; t < T_STEPS; ++t){
    if (tid == 0){
      if (!sdead){
        if (!(waitge(&P.cnt[0], (uint32_t)(NA * t)) && waitge(&P.cnt[64], (uint32_t)t))) sdead = 1;
      }
    }
    __syncthreads();
    const float* hp = P.h0buf + (((t & 1) ^ 1) * HD);
    const float* ep = P.embbuf + (((t & 1) ^ 1) * EMBD);
    xv[tid] = gload(hp + tid);                    // tid < 1024 < 1536
    {
      int i = tid + 1024;
      if (i < 1664) xv[i] = (i < HD) ? gload(hp + i) : gload(ep + (i - HD));
    }
    __syncthreads();
    float a0 = 0.f, a1 = 0.f, a2 = 0.f, a3 = 0.f;
    const int kb = l * 26;
#pragma unroll
    for (int p = 0; p < 13; ++p){
      float2 x2 = *(const float2*)&xv[kb + 2 * p];
      uint32_t u0 = wr[0][p], u1 = wr[1][p], u2 = wr[2][p], u3 = wr[3][p];
      a0 += bf_lo(u0) * x2.x + bf_hi(u0) * x2.y;
      a1 += bf_lo(u1) * x2.x + bf_hi(u1) * x2.y;
      a2 += bf_lo(u2) * x2.x + bf_hi(u2) * x2.y;
      a3 += bf_lo(u3) * x2.x + bf_hi(u3) * x2.y;
    }
#pragma unroll
    for (int m = 1; m < 64; m <<= 1){
      a0 += __shfl_xor(a0, m, 64);
      a1 += __shfl_xor(a1, m, 64);
      a2 += __shfl_xor(a2, m, 64);
      a3 += __shfl_xor(a3, m, 64);
    }
    const float* pre = P.PRE + (size_t)t * 6144;
    float gi = sigm(a0 + pre[O]);
    float gf = sigm(a1 + pre[HD + O]);
    float gg = tanhf(a2 + pre[2 * HD + O]);
    float go = sigm(a3 + pre[3 * HD + O]);
    cst = gf * cst + gi * gg;
    float hn = go * tanhf(cst);
    if (l == 0){
      gstore(P.h0buf + (t & 1) * HD + O, hn);
      __threadfence();
    }
    __syncthreads();
    if (tid == 0) __hip_atomic_fetch_add(&P.cnt[0], 1u, __ATOMIC_RELEASE, __HIP_MEMORY_SCOPE_AGENT);
  }
}

// ---------------- group B: LSTM layer 1 (128 blocks, 12 outputs each) ----------------
// 48 gate-rows; wave w owns rows idx=3w..3w+2 (idx = g*12 + o); lane chunk = 50 (K padded 3200)
__device__ __forceinline__ float bsrc(const Params& P, int r, int k){
  if (k < HD) return P.Wih1[(size_t)r * HD + k];
  if (k < 2 * HD) return P.Whh1[(size_t)r * HD + (k - HD)];
  return 0.f;
}
__device__ void run_B(const Params& P, int bidb){
  const int tid = threadIdx.x;
  const int w = tid >> 6, l = tid & 63;
  const int base = bidb * 12;
  __shared__ float xv[3200];
  __shared__ float g1lds[48];
  __shared__ float c1lds[12];
  __shared__ float h1lds[12];
  __shared__ int sdead;
  if (tid == 0) sdead = 0;
  uint32_t wr[3][25];
  float bias[3];
#pragma unroll
  for (int j = 0; j < 3; ++j){
    int idx = 3 * w + j;
    int g = idx / 12, o = idx % 12;
    int r = g * HD + base + o;
    bias[j] = P.bih1[r] + P.bhh1[r];
#pragma unroll
    for (int p = 0; p < 25; ++p){
      int k0 = l * 50 + 2 * p;
      wr[j][p] = packbf(bsrc(P, r, k0), bsrc(P, r, k0 + 1));
    }
  }
  const int jrow = tid >> 2, cpart = tid & 3;
  float wc0 = 0.f, wc1 = 0.f, wc2 = 0.f;
  if (tid < 512){
    const float* wcp = P.Wc + (size_t)jrow * HD + base + cpart * 3;
    wc0 = wcp[0]; wc1 = wcp[1]; wc2 = wcp[2];
  }
  if (tid < 12) c1lds[tid] = P.c0in[HD + base + tid];
  if (tid < 128) xv[3072 + tid] = 0.f;
  __syncthreads();
  for (int t = 0; t < T_STEPS; ++t){
    if (tid == 0){
      if (!sdead){
        if (!(waitge(&P.cnt[0], (uint32_t)(NA * (t + 1))) && waitge(&P.cnt[32], (uint32_t)(NB * t)))) sdead = 1;
      }
    }
    __syncthreads();
    const float* h0p = P.h0buf + (t & 1) * HD;
    const float* h1p = P.h1buf + (((t & 1) ^ 1) * HD);
    for (int i = tid; i < 3072; i += 1024)
      xv[i] = (i < HD) ? gload(h0p + i) : gload(h1p + (i - HD));
    __syncthreads();
    float a0 = 0.f, a1 = 0.f, a2 = 0.f;
    const int kb = l * 50;
#pragma unroll
    for (int p = 0; p < 25; ++p){
      float2 x2 = *(const float2*)&xv[kb + 2 * p];
      uint32_t u0 = wr[0][p], u1 = wr[1][p], u2 = wr[2][p];
      a0 += bf_lo(u0) * x2.x + bf_hi(u0) * x2.y;
      a1 += bf_lo(u1) * x2.x + bf_hi(u1) * x2.y;
      a2 += bf_lo(u2) * x2.x + bf_hi(u2) * x2.y;
    }
#pragma unroll
    for (int m = 1; m < 64; m <<= 1){
      a0 += __shfl_xor(a0, m, 64);
      a1 += __shfl_xor(a1, m, 64);
      a2 += __shfl_xor(a2, m, 64);
    }
    if (l == 0){
      g1lds[3 * w + 0] = a0 + bias[0];
      g1lds[3 * w + 1] = a1 + bias[1];
      g1lds[3 * w + 2] = a2 + bias[2];
    }
    __syncthreads();
    if (tid < 12){
      int o = tid;
      float gi = sigm(g1lds[o]);
      float gf = sigm(g1lds[12 + o]);
      float gg = tanhf(g1lds[24 + o]);
      float go = sigm(g1lds[36 + o]);
      float c = gf * c1lds[o] + gi * gg;
      c1lds[o] = c;
      float hn = go * tanhf(c);
      h1lds[o] = hn;
      gstore(P.h1buf + (t & 1) * HD + base + o, hn);
    }
    __syncthreads();
    if (tid < 512){
      float pp = wc0 * h1lds[cpart * 3] + wc1 * h1lds[cpart * 3 + 1] + wc2 * h1lds[cpart * 3 + 2];
      pp += __shfl_xor(pp, 1, 64);
      pp += __shfl_xor(pp, 2, 64);
      if (cpart == 0) gstore(P.PART + bidb * 128 + jrow, pp);
    }
    __threadfence();
    __syncthreads();
    if (tid == 0) __hip_atomic_fetch_add(&P.cnt[32], 1u, __ATOMIC_RELEASE, __HIP_MEMORY_SCOPE_AGENT);
  }
}

// ---------------- group C: logit-sum + softmax + out + emb (1 block) ----------------
__device__ void run_C(const Params& P){
  const int tid = threadIdx.x;
  __shared__ float partred[8 * 128];
  __shared__ float lg[128];
  __shared__ float plds[128];
  __shared__ float bcs[128];
  __shared__ float red2[2];
  __shared__ int sdead;
  float wm[16];
  const int e = tid >> 3, jc = tid & 7;
#pragma unroll
  for (int i = 0; i < 16; ++i) wm[i] = P.Wmap[(size_t)e * 128 + jc * 16 + i];
  float bm = P.bmap[e];
  if (tid < 128) bcs[tid] = P.bc[tid];
  if (tid == 0) sdead = 0;
  __syncthreads();
  for (int t = 0; t < T_STEPS; ++t){
    if (tid == 0){
      if (!sdead){
        if (!waitge(&P.cnt[32], (uint32_t)(NB * (t + 1)))) sdead = 1;
      }
    }
    __syncthreads();
    const int j = tid & 127, b8 = tid >> 7;
    float s = 0.f;
#pragma unroll
    for (int i = 0; i < 16; ++i) s += gload(P.PART + (b8 * 16 + i) * 128 + j);
    partred[b8 * 128 + j] = s;
    __syncthreads();
    if (tid < 128){
      float lt = bcs[tid];
#pragma unroll
      for (int i = 0; i < 8; ++i) lt += partred[i * 128 + tid];
      lg[tid] = lt;
    }
    __syncthreads();
    if (tid < 64){
      float m = fmaxf(lg[tid], lg[tid + 64]);
#pragma unroll
      for (int k = 1; k < 64; k <<= 1) m = fmaxf(m, __shfl_xor(m, k, 64));
      float sd = __expf(lg[tid] - m) + __expf(lg[tid + 64] - m);
#pragma unroll
      for (int k = 1; k < 64; k <<= 1) sd += __shfl_xor(sd, k, 64);
      if (tid == 0){ red2[0] = m; red2[1] = 1.f / sd; }
    }
    __syncthreads();
    if (tid < 128){
      float pv = __expf(lg[tid] - red2[0]) * red2[1];
      plds[tid] = pv;
      P.out[(size_t)t * 128 + tid] = pv;
    }
    __syncthreads();
    float a = 0.f;
#pragma unroll
    for (int i = 0; i < 16; ++i) a += wm[i] * plds[jc * 16 + i];
    a += __shfl_xor(a, 1, 64);
    a += __shfl_xor(a, 2, 64);
    a += __shfl_xor(a, 4, 64);
    if (jc == 0) gstore(P.embbuf + (t & 1) * EMBD + e, a + bm);
    __threadfence();
    __syncthreads();
    if (tid == 0) __hip_atomic_fetch_add(&P.cnt[64], 1u, __ATOMIC_RELEASE, __HIP_MEMORY_SCOPE_AGENT);
  }
}

__global__ __launch_bounds__(1024) void k_lstm(Params P){
  int bid = blockIdx.x;
  if (bid < NA) run_A(P, bid);
  else if (bid < NA + NB) run_B(P, bid - NA);
  else run_C(P);
}

// ---------------- pre-kernels ----------------
__global__ void k_init(const float* h0in, float* h0buf, float* h1buf, float* embbuf, uint32_t* cnt){
  int tid = threadIdx.x;
  for (int i = tid; i < HD; i += 256){
    float a = h0in[i], b = h0in[HD + i];
    h0buf[i] = a; h0buf[HD + i] = a;
    h1buf[i] = b; h1buf[HD + i] = b;
  }
  if (tid < 128){ embbuf[tid] = 0.f; embbuf[128 + tid] = 0.f; }
  if (tid < 3) cnt[tid * 32] = 0u;
}

// PRE[t][r] = b_ih0[r]+b_hh0[r] + sum_k W_ih0[r][k]*x[t][k], k<118
__global__ void k_pre(const float* x, const float* Wih0, const float* bih0, const float* bhh0, float* PRE){
  int tb = blockIdx.x >> 2;   // 64 tiles of 32 timesteps
  int rc = blockIdx.x & 3;    // 4 chunks of 1536 rows
  int tid = threadIdx.x;      // 256
  __shared__ float xl[32 * XDIM];
  for (int i = tid; i < 32 * XDIM; i += 256){
    int tt = i / XDIM, k = i % XDIM;
    xl[i] = x[(size_t)(tb * 32 + tt) * XDIM + k];
  }
  __syncthreads();
  for (int rr = 0; rr < 6; ++rr){
    int r = rc * HD + rr * 256 + tid;
    float acc[32];
#pragma unroll
    for (int t = 0; t < 32; ++t) acc[t] = 0.f;
    const float* wrow = Wih0 + (size_t)r * (XDIM + EMBD);
    for (int k = 0; k < XDIM; ++k){
      float wv = wrow[k];
#pragma unroll
      for (int t = 0; t < 32; ++t) acc[t] += wv * xl[t * XDIM + k];
    }
    float bb = bih0[r] + bhh0[r];
    for (int t = 0; t < 32; ++t)
      PRE[(size_t)(tb * 32 + t) * 6144 + r] = acc[t] + bb;
  }
}

// Wc = W_out @ W_hl  (128 x 1536, K=1024); bc = W_out @ b_hl + b_out
__global__ void k_wc(const float* Whl, const float* Wout, const float* bhl, const float* bout,
                     float* Wc, float* bc){
  if (blockIdx.x == 96){
    int j = threadIdx.x;
    if (j < 128){
      float a = 0.f;
      for (int m = 0; m < 1024; ++m) a += Wout[(size_t)j * 1024 + m] * bhl[m];
      bc[j] = a + bout[j];
    }
    return;
  }
  int kt = blockIdx.x % 6, jt = blockIdx.x / 6;
  __shared__ float wo[8 * 1024];
  int tid = threadIdx.x;  // 256
  for (int i = tid; i < 8 * 1024; i += 256) wo[i] = Wout[(size_t)(jt * 8) * 1024 + i];
  __syncthreads();
  int k = kt * 256 + tid;
  float acc[8];
#pragma unroll
  for (int jj = 0; jj < 8; ++jj) acc[jj] = 0.f;
  for (int m = 0; m < 1024; ++m){
    float wl = Whl[(size_t)m * HD + k];
#pragma unroll
    for (int jj = 0; jj < 8; ++jj) acc[jj] += wo[jj * 1024 + m] * wl;
  }
#pragma unroll
  for (int jj = 0; jj < 8; ++jj) Wc[(size_t)(jt * 8 + jj) * HD + k] = acc[jj];
}

__global__ void k_sentinel(float* out){ out[0] = 1.0e6f; }

extern "C" void kernel_launch(void* const* d_in, const int* in_sizes, int n_in,
                              void* d_out, int out_size, void* d_ws, size_t ws_size,
                              hipStream_t stream){
  (void)in_sizes; (void)n_in; (void)out_size;
  const float* x    = (const float*)d_in[0];
  const float* h0in = (const float*)d_in[1];
  const float* c0in = (const float*)d_in[2];
  const float* Wih0 = (const float*)d_in[3];
  const float* Whh0 = (const float*)d_in[4];
  const float* bih0 = (const float*)d_in[5];
  const float* bhh0 = (const float*)d_in[6];
  const float* Wih1 = (const float*)d_in[7];
  const float* Whh1 = (const float*)d_in[8];
  const float* bih1 = (const float*)d_in[9];
  const float* bhh1 = (const float*)d_in[10];
  const float* Whl  = (const float*)d_in[11];
  const float* bhl  = (const float*)d_in[12];
  const float* Wout = (const float*)d_in[13];
  const float* bout = (const float*)d_in[14];
  const float* Wmap = (const float*)d_in[15];
  const float* bmap = (const float*)d_in[16];
  float* out = (float*)d_out;
  float* ws = (float*)d_ws;

  size_t off = 0;
  float* PRE    = ws + off; off += (size_t)T_STEPS * 6144;
  float* Wc     = ws + off; off += 128 * HD;
  float* bc     = ws + off; off += 128;
  float* h0buf  = ws + off; off += 2 * HD;
  float* h1buf  = ws + off; off += 2 * HD;
  float* embbuf = ws + off; off += 2 * EMBD;
  float* PART   = ws + off; off += 128 * 128;
  off = (off + 63) & ~(size_t)63;
  uint32_t* cnt = (uint32_t*)(ws + off); off += 96;

  if (ws_size < off * sizeof(float) + 1024){
    hipLaunchKernelGGL(k_sentinel, dim3(1), dim3(1), 0, stream, out);
    return;
  }

  hipLaunchKernelGGL(k_init, dim3(1), dim3(256), 0, stream, h0in, h0buf, h1buf, embbuf, cnt);
  hipLaunchKernelGGL(k_pre, dim3(256), dim3(256), 0, stream, x, Wih0, bih0, bhh0, PRE);
  hipLaunchKernelGGL(k_wc, dim3(97), dim3(256), 0, stream, Whl, Wout, bhl, bout, Wc, bc);

  Params P;
  P.x = x; P.h0in = h0in; P.c0in = c0in;
  P.Wih0 = Wih0; P.Whh0 = Whh0; P.bih0 = bih0; P.bhh0 = bhh0;
  P.Wih1 = Wih1; P.Whh1 = Whh1; P.bih1 = bih1; P.bhh1 = bhh1;
  P.Whl = Whl; P.bhl = bhl; P.Wout = Wout; P.bout = bout; P.Wmap = Wmap; P.bmap = bmap;
  P.PRE = PRE; P.Wc = Wc; P.bc = bc;
  P.h0buf = h0buf; P.h1buf = h1buf; P.embbuf = embbuf; P.PART = PART;
  P.cnt = cnt; P.out = out;

  hipLaunchKernelGGL(k_lstm, dim3(NBLK), dim3(1024), 0, stream, P);
}

// Round 2
// 67305.054 us; speedup vs baseline: 6.7585x; 6.7585x over previous
//
#include <hip/hip_runtime.h>
#include <math.h>
#include <stdint.h>

#define T_STEPS 2048
#define XDIM 118
#define EMBD 128
#define HD 1536
#define NA 96
#define NB 128
#define NBLK (NA + NB + 1)

struct Params {
  const float *x, *h0in, *c0in;
  const float *Wih0, *Whh0, *bih0, *bhh0;
  const float *Wih1, *Whh1, *bih1, *bhh1;
  const float *Whl, *bhl, *Wout, *bout, *Wmap, *bmap;
  float *PRE, *Wc, *bc, *h0buf, *h1buf, *embbuf, *PART;
  uint32_t *cnt;   // cnt[0]=h0-done, cnt[32]=h1-done, cnt[64]=emb-done (separate lines)
  float *out;
};

__device__ __forceinline__ float bf_lo(uint32_t u){ return __uint_as_float(u << 16); }
__device__ __forceinline__ float bf_hi(uint32_t u){ return __uint_as_float(u & 0xffff0000u); }
__device__ __forceinline__ uint32_t packbf(float a, float b){
  uint32_t ua = __float_as_uint(a), ub = __float_as_uint(b);
  ua = (ua + 0x7fffu + ((ua >> 16) & 1u)) >> 16;           // RNE to bf16 (low half)
  ub = (ub + 0x7fffu + ((ub >> 16) & 1u)) & 0xffff0000u;   // RNE to bf16 (high half)
  return (ua & 0xffffu) | ub;
}
// All cross-block data goes through agent-scope relaxed atomics: sc0/sc1
// write-through/read-through at the device coherence point. Never stale, no
// buffer_inv / buffer_wbl2 needed. Ordering data->flag is provided by
// __syncthreads() (compiler drains vmcnt before s_barrier) + program order.
__device__ __forceinline__ float gload(const float* p){
  return __hip_atomic_load(p, __ATOMIC_RELAXED, __HIP_MEMORY_SCOPE_AGENT);
}
__device__ __forceinline__ void gstore(float* p, float v){
  __hip_atomic_store(p, v, __ATOMIC_RELAXED, __HIP_MEMORY_SCOPE_AGENT);
}
__device__ __forceinline__ int waitge(uint32_t* p, uint32_t tgt){
  uint32_t n = 0;
  while (__hip_atomic_load(p, __ATOMIC_RELAXED, __HIP_MEMORY_SCOPE_AGENT) < tgt){
    __builtin_amdgcn_s_sleep(1);          // 64-cycle backoff, keep fabric calm
    if (++n > 20000000u) return 0;        // bail instead of hanging the harness
  }
  return 1;
}
__device__ __forceinline__ void signal(uint32_t* p){
  __hip_atomic_fetch_add(p, 1u, __ATOMIC_RELAXED, __HIP_MEMORY_SCOPE_AGENT);
}
__device__ __forceinline__ float sigm(float x){ return 1.f / (1.f + __expf(-x)); }

// ---------------- group A: LSTM layer 0 (96 blocks, 16 outputs each) ----------------
// wave w owns all 4 gates of output O = bid*16+w.
// K-layout: lane l owns k = l + 64*j, j=0..25.  j<24 -> h0(t-1) (k<1536),
// j=24,25 -> emb(t-1) (k=1536..1663). Packed pairs: wr[g][p] = (k=l+128p, k=l+128p+64).
// Phase 1 (p=0..11) needs only cnt0>=96t; phase 2 (p=12) needs emb (cnt64>=t).
__device__ __forceinline__ float asrc(const Params& P, int r, int k){
  if (k < HD) return P.Whh0[(size_t)r * HD + k];
  return P.Wih0[(size_t)r * (XDIM + EMBD) + XDIM + (k - HD)];
}
__device__ void run_A(const Params& P, int bid){
  const int tid = threadIdx.x;
  const int w = tid >> 6, l = tid & 63;
  const int O = bid * 16 + w;
  __shared__ float xv[1664];
  __shared__ int sdead;
  if (tid == 0) sdead = 0;
  uint32_t wr[4][13];
#pragma unroll
  for (int g = 0; g < 4; ++g){
    int r = g * HD + O;
#pragma unroll
    for (int p = 0; p < 13; ++p)
      wr[g][p] = packbf(asrc(P, r, l + 128 * p), asrc(P, r, l + 128 * p + 64));
  }
  float cst = P.c0in[O];
  __syncthreads();
  for (int t = 0; t < T_STEPS; ++t){
    if (tid == 0 && !sdead){
      if (!waitge(&P.cnt[0], (uint32_t)(NA * t))) sdead = 1;
    }
    __syncthreads();
    const float* hp = P.h0buf + (((t & 1) ^ 1) * HD);
    for (int i = tid; i < HD; i += 1024) xv[i] = gload(hp + i);
    __syncthreads();
    float a0 = 0.f, a1 = 0.f, a2 = 0.f, a3 = 0.f;
#pragma unroll
    for (int p = 0; p < 12; ++p){
      float xa = xv[l + 128 * p], xb = xv[l + 128 * p + 64];
      uint32_t u0 = wr[0][p], u1 = wr[1][p], u2 = wr[2][p], u3 = wr[3][p];
      a0 += bf_lo(u0) * xa + bf_hi(u0) * xb;
      a1 += bf_lo(u1) * xa + bf_hi(u1) * xb;
      a2 += bf_lo(u2) * xa + bf_hi(u2) * xb;
      a3 += bf_lo(u3) * xa + bf_hi(u3) * xb;
    }
    if (tid == 0 && !sdead){
      if (!waitge(&P.cnt[64], (uint32_t)t)) sdead = 1;
    }
    __syncthreads();
    if (tid < EMBD) xv[HD + tid] = gload(P.embbuf + (((t & 1) ^ 1) * EMBD) + tid);
    __syncthreads();
    {
      float xa = xv[l + 1536], xb = xv[l + 1600];
      uint32_t u0 = wr[0][12], u1 = wr[1][12], u2 = wr[2][12], u3 = wr[3][12];
      a0 += bf_lo(u0) * xa + bf_hi(u0) * xb;
      a1 += bf_lo(u1) * xa + bf_hi(u1) * xb;
      a2 += bf_lo(u2) * xa + bf_hi(u2) * xb;
      a3 += bf_lo(u3) * xa + bf_hi(u3) * xb;
    }
#pragma unroll
    for (int m = 1; m < 64; m <<= 1){
      a0 += __shfl_xor(a0, m, 64);
      a1 += __shfl_xor(a1, m, 64);
      a2 += __shfl_xor(a2, m, 64);
      a3 += __shfl_xor(a3, m, 64);
    }
    const float* pre = P.PRE + (size_t)t * 6144;
    float gi = sigm(a0 + pre[O]);
    float gf = sigm(a1 + pre[HD + O]);
    float gg = tanhf(a2 + pre[2 * HD + O]);
    float go = sigm(a3 + pre[3 * HD + O]);
    cst = gf * cst + gi * gg;
    float hn = go * tanhf(cst);
    if (l == 0) gstore(P.h0buf + (t & 1) * HD + O, hn);
    __syncthreads();   // drains vmcnt: h-stores are at the coherence point
    if (tid == 0) signal(&P.cnt[0]);
  }
}

// ---------------- group B: LSTM layer 1 (128 blocks, 12 outputs each) ----------------
// 48 gate-rows; wave w owns rows idx=3w..3w+2 (idx = g*12 + o).
// K-layout: xv[0..1536)=h0(t), xv[1536..3072)=h1(t-1); lane k = l + 64j, j=0..47.
// Phase 1 (p=12..23, h1 side) needs only cnt32>=128t; phase 2 (p=0..11) needs A@t.
__device__ __forceinline__ float bsrc(const Params& P, int r, int k){
  if (k < HD) return P.Wih1[(size_t)r * HD + k];
  return P.Whh1[(size_t)r * HD + (k - HD)];
}
__device__ void run_B(const Params& P, int bidb){
  const int tid = threadIdx.x;
  const int w = tid >> 6, l = tid & 63;
  const int base = bidb * 12;
  __shared__ float xv[3072];
  __shared__ float g1lds[48];
  __shared__ float c1lds[12];
  __shared__ float h1lds[12];
  __shared__ int sdead;
  if (tid == 0) sdead = 0;
  uint32_t wr[3][24];
  float bias[3];
#pragma unroll
  for (int jj = 0; jj < 3; ++jj){
    int idx = 3 * w + jj;
    int g = idx / 12, o = idx % 12;
    int r = g * HD + base + o;
    bias[jj] = P.bih1[r] + P.bhh1[r];
#pragma unroll
    for (int p = 0; p < 24; ++p)
      wr[jj][p] = packbf(bsrc(P, r, l + 128 * p), bsrc(P, r, l + 128 * p + 64));
  }
  const int jrow = tid >> 2, cpart = tid & 3;
  float wc0 = 0.f, wc1 = 0.f, wc2 = 0.f;
  if (tid < 512){
    const float* wcp = P.Wc + (size_t)jrow * HD + base + cpart * 3;
    wc0 = wcp[0]; wc1 = wcp[1]; wc2 = wcp[2];
  }
  if (tid < 12) c1lds[tid] = P.c0in[HD + base + tid];
  __syncthreads();
  for (int t = 0; t < T_STEPS; ++t){
    if (tid == 0 && !sdead){
      if (!waitge(&P.cnt[32], (uint32_t)(NB * t))) sdead = 1;
    }
    __syncthreads();
    const float* h1p = P.h1buf + (((t & 1) ^ 1) * HD);
    for (int i = tid; i < HD; i += 1024) xv[HD + i] = gload(h1p + i);
    __syncthreads();
    float a0 = 0.f, a1 = 0.f, a2 = 0.f;
#pragma unroll
    for (int p = 12; p < 24; ++p){
      float xa = xv[l + 128 * p], xb = xv[l + 128 * p + 64];
      uint32_t u0 = wr[0][p], u1 = wr[1][p], u2 = wr[2][p];
      a0 += bf_lo(u0) * xa + bf_hi(u0) * xb;
      a1 += bf_lo(u1) * xa + bf_hi(u1) * xb;
      a2 += bf_lo(u2) * xa + bf_hi(u2) * xb;
    }
    if (tid == 0 && !sdead){
      if (!waitge(&P.cnt[0], (uint32_t)(NA * (t + 1)))) sdead = 1;
    }
    __syncthreads();
    const float* h0p = P.h0buf + (t & 1) * HD;
    for (int i = tid; i < HD; i += 1024) xv[i] = gload(h0p + i);
    __syncthreads();
#pragma unroll
    for (int p = 0; p < 12; ++p){
      float xa = xv[l + 128 * p], xb = xv[l + 128 * p + 64];
      uint32_t u0 = wr[0][p], u1 = wr[1][p], u2 = wr[2][p];
      a0 += bf_lo(u0) * xa + bf_hi(u0) * xb;
      a1 += bf_lo(u1) * xa + bf_hi(u1) * xb;
      a2 += bf_lo(u2) * xa + bf_hi(u2) * xb;
    }
#pragma unroll
    for (int m = 1; m < 64; m <<= 1){
      a0 += __shfl_xor(a0, m, 64);
      a1 += __shfl_xor(a1, m, 64);
      a2 += __shfl_xor(a2, m, 64);
    }
    if (l == 0){
      g1lds[3 * w + 0] = a0 + bias[0];
      g1lds[3 * w + 1] = a1 + bias[1];
      g1lds[3 * w + 2] = a2 + bias[2];
    }
    __syncthreads();
    if (tid < 12){
      int o = tid;
      float gi = sigm(g1lds[o]);
      float gf = sigm(g1lds[12 + o]);
      float gg = tanhf(g1lds[24 + o]);
      float go = sigm(g1lds[36 + o]);
      float c = gf * c1lds[o] + gi * gg;
      c1lds[o] = c;
      float hn = go * tanhf(c);
      h1lds[o] = hn;
      gstore(P.h1buf + (t & 1) * HD + base + o, hn);
    }
    __syncthreads();
    if (tid < 512){
      float pp = wc0 * h1lds[cpart * 3] + wc1 * h1lds[cpart * 3 + 1] + wc2 * h1lds[cpart * 3 + 2];
      pp += __shfl_xor(pp, 1, 64);
      pp += __shfl_xor(pp, 2, 64);
      if (cpart == 0) gstore(P.PART + bidb * 128 + jrow, pp);
    }
    __syncthreads();   // drains vmcnt: h1 + PART stores at coherence point
    if (tid == 0) signal(&P.cnt[32]);
  }
}

// ---------------- group C: logit-sum + softmax + out + emb (1 block) ----------------
__device__ void run_C(const Params& P){
  const int tid = threadIdx.x;
  __shared__ float partred[8 * 128];
  __shared__ float lg[128];
  __shared__ float plds[128];
  __shared__ float bcs[128];
  __shared__ float red2[2];
  __shared__ int sdead;
  float wm[16];
  const int e = tid >> 3, jc = tid & 7;
#pragma unroll
  for (int i = 0; i < 16; ++i) wm[i] = P.Wmap[(size_t)e * 128 + jc * 16 + i];
  float bm = P.bmap[e];
  if (tid < 128) bcs[tid] = P.bc[tid];
  if (tid == 0) sdead = 0;
  __syncthreads();
  for (int t = 0; t < T_STEPS; ++t){
    if (tid == 0 && !sdead){
      if (!waitge(&P.cnt[32], (uint32_t)(NB * (t + 1)))) sdead = 1;
    }
    __syncthreads();
    const int j = tid & 127, b8 = tid >> 7;
    float s = 0.f;
#pragma unroll
    for (int i = 0; i < 16; ++i) s += gload(P.PART + (b8 * 16 + i) * 128 + j);
    partred[b8 * 128 + j] = s;
    __syncthreads();
    if (tid < 128){
      float lt = bcs[tid];
#pragma unroll
      for (int i = 0; i < 8; ++i) lt += partred[i * 128 + tid];
      lg[tid] = lt;
    }
    __syncthreads();
    if (tid < 64){
      float m = fmaxf(lg[tid], lg[tid + 64]);
#pragma unroll
      for (int k = 1; k < 64; k <<= 1) m = fmaxf(m, __shfl_xor(m, k, 64));
      float sd = __expf(lg[tid] - m) + __expf(lg[tid + 64] - m);
#pragma unroll
      for (int k = 1; k < 64; k <<= 1) sd += __shfl_xor(sd, k, 64);
      if (tid == 0){ red2[0] = m; red2[1] = 1.f / sd; }
    }
    __syncthreads();
    if (tid < 128){
      float pv = __expf(lg[tid] - red2[0]) * red2[1];
      plds[tid] = pv;
      P.out[(size_t)t * 128 + tid] = pv;
    }
    __syncthreads();
    float a = 0.f;
#pragma unroll
    for (int i = 0; i < 16; ++i) a += wm[i] * plds[jc * 16 + i];
    a += __shfl_xor(a, 1, 64);
    a += __shfl_xor(a, 2, 64);
    a += __shfl_xor(a, 4, 64);
    if (jc == 0) gstore(P.embbuf + (t & 1) * EMBD + e, a + bm);
    __syncthreads();   // drains vmcnt: emb stores at coherence point
    if (tid == 0) signal(&P.cnt[64]);
  }
}

// launch_bounds(1024, 4): 4 waves/EU = 16 waves/CU = 1 block/CU -> 128-VGPR cap.
// Round 1 used the default (8 waves/EU, 64 VGPRs) and SPILLED the register-
// resident weights to scratch -> 22 GB HBM traffic. Do not lower this.
__global__ __launch_bounds__(1024, 4) void k_lstm(Params P){
  int bid = blockIdx.x;
  if (bid < NA) run_A(P, bid);
  else if (bid < NA + NB) run_B(P, bid - NA);
  else run_C(P);
}

// ---------------- pre-kernels ----------------
__global__ void k_init(const float* h0in, float* h0buf, float* h1buf, float* embbuf, uint32_t* cnt){
  int tid = threadIdx.x;
  for (int i = tid; i < HD; i += 256){
    float a = h0in[i], b = h0in[HD + i];
    h0buf[i] = a; h0buf[HD + i] = a;
    h1buf[i] = b; h1buf[HD + i] = b;
  }
  if (tid < 128){ embbuf[tid] = 0.f; embbuf[128 + tid] = 0.f; }
  if (tid < 3) cnt[tid * 32] = 0u;
}

// PRE[t][r] = b_ih0[r]+b_hh0[r] + sum_k W_ih0[r][k]*x[t][k], k<118
__global__ void k_pre(const float* x, const float* Wih0, const float* bih0, const float* bhh0, float* PRE){
  int tb = blockIdx.x >> 2;
  int rc = blockIdx.x & 3;
  int tid = threadIdx.x;
  __shared__ float xl[32 * XDIM];
  for (int i = tid; i < 32 * XDIM; i += 256){
    int tt = i / XDIM, k = i % XDIM;
    xl[i] = x[(size_t)(tb * 32 + tt) * XDIM + k];
  }
  __syncthreads();
  for (int rr = 0; rr < 6; ++rr){
    int r = rc * HD + rr * 256 + tid;
    float acc[32];
#pragma unroll
    for (int t = 0; t < 32; ++t) acc[t] = 0.f;
    const float* wrow = Wih0 + (size_t)r * (XDIM + EMBD);
    for (int k = 0; k < XDIM; ++k){
      float wv = wrow[k];
#pragma unroll
      for (int t = 0; t < 32; ++t) acc[t] += wv * xl[t * XDIM + k];
    }
    float bb = bih0[r] + bhh0[r];
    for (int t = 0; t < 32; ++t)
      PRE[(size_t)(tb * 32 + t) * 6144 + r] = acc[t] + bb;
  }
}

// Wc = W_out @ W_hl  (128 x 1536, K=1024); bc = W_out @ b_hl + b_out
__global__ void k_wc(const float* Whl, const float* Wout, const float* bhl, const float* bout,
                     float* Wc, float* bc){
  if (blockIdx.x == 96){
    int j = threadIdx.x;
    if (j < 128){
      float a = 0.f;
      for (int m = 0; m < 1024; ++m) a += Wout[(size_t)j * 1024 + m] * bhl[m];
      bc[j] = a + bout[j];
    }
    return;
  }
  int kt = blockIdx.x % 6, jt = blockIdx.x / 6;
  __shared__ float wo[8 * 1024];
  int tid = threadIdx.x;
  for (int i = tid; i < 8 * 1024; i += 256) wo[i] = Wout[(size_t)(jt * 8) * 1024 + i];
  __syncthreads();
  int k = kt * 256 + tid;
  float acc[8];
#pragma unroll
  for (int jj = 0; jj < 8; ++jj) acc[jj] = 0.f;
  for (int m = 0; m < 1024; ++m){
    float wl = Whl[(size_t)m * HD + k];
#pragma unroll
    for (int jj = 0; jj < 8; ++jj) acc[jj] += wo[jj * 1024 + m] * wl;
  }
#pragma unroll
  for (int jj = 0; jj < 8; ++jj) Wc[(size_t)(jt * 8 + jj) * HD + k] = acc[jj];
}

__global__ void k_sentinel(float* out){ out[0] = 1.0e6f; }

extern "C" void kernel_launch(void* const* d_in, const int* in_sizes, int n_in,
                              void* d_out, int out_size, void* d_ws, size_t ws_size,
                              hipStream_t stream){
  (void)in_sizes; (void)n_in; (void)out_size;
  const float* x    = (const float*)d_in[0];
  const float* h0in = (const float*)d_in[1];
  const float* c0in = (const float*)d_in[2];
  const float* Wih0 = (const float*)d_in[3];
  const float* Whh0 = (const float*)d_in[4];
  const float* bih0 = (const float*)d_in[5];
  const float* bhh0 = (const float*)d_in[6];
  const float* Wih1 = (const float*)d_in[7];
  const float* Whh1 = (const float*)d_in[8];
  const float* bih1 = (const float*)d_in[9];
  const float* bhh1 = (const float*)d_in[10];
  const float* Whl  = (const float*)d_in[11];
  const float* bhl  = (const float*)d_in[12];
  const float* Wout = (const float*)d_in[13];
  const float* bout = (const float*)d_in[14];
  const float* Wmap = (const float*)d_in[15];
  const float* bmap = (const float*)d_in[16];
  float* out = (float*)d_out;
  float* ws = (float*)d_ws;

  size_t off = 0;
  float* PRE    = ws + off; off += (size_t)T_STEPS * 6144;
  float* Wc     = ws + off; off += 128 * HD;
  float* bc     = ws + off; off += 128;
  float* h0buf  = ws + off; off += 2 * HD;
  float* h1buf  = ws + off; off += 2 * HD;
  float* embbuf = ws + off; off += 2 * EMBD;
  float* PART   = ws + off; off += 128 * 128;
  off = (off + 63) & ~(size_t)63;
  uint32_t* cnt = (uint32_t*)(ws + off); off += 96;

  if (ws_size < off * sizeof(float) + 1024){
    hipLaunchKernelGGL(k_sentinel, dim3(1), dim3(1), 0, stream, out);
    return;
  }

  hipLaunchKernelGGL(k_init, dim3(1), dim3(256), 0, stream, h0in, h0buf, h1buf, embbuf, cnt);
  hipLaunchKernelGGL(k_pre, dim3(256), dim3(256), 0, stream, x, Wih0, bih0, bhh0, PRE);
  hipLaunchKernelGGL(k_wc, dim3(97), dim3(256), 0, stream, Whl, Wout, bhl, bout, Wc, bc);

  Params P;
  P.x = x; P.h0in = h0in; P.c0in = c0in;
  P.Wih0 = Wih0; P.Whh0 = Whh0; P.bih0 = bih0; P.bhh0 = bhh0;
  P.Wih1 = Wih1; P.Whh1 = Whh1; P.bih1 = bih1; P.bhh1 = bhh1;
  P.Whl = Whl; P.bhl = bhl; P.Wout = Wout; P.bout = bout; P.Wmap = Wmap; P.bmap = bmap;
  P.PRE = PRE; P.Wc = Wc; P.bc = bc;
  P.h0buf = h0buf; P.h1buf = h1buf; P.embbuf = embbuf; P.PART = PART;
  P.cnt = cnt; P.out = out;

  hipLaunchKernelGGL(k_lstm, dim3(NBLK), dim3(1024), 0, stream, P);
}

// Round 3
// 58347.015 us; speedup vs baseline: 7.7962x; 1.1535x over previous
//
#include <hip/hip_runtime.h>
#include <math.h>
#include <stdint.h>

#define T_STEPS 2048
#define XDIM 118
#define EMBD 128
#define HD 1536
#define NA 96
#define NB 128
#define NBLK (NA + NB + 1)

struct Params {
  const float *x, *h0in, *c0in;
  const float *Wih0, *Whh0, *bih0, *bhh0;
  const float *Wih1, *Whh1, *bih1, *bhh1;
  const float *Whl, *bhl, *Wout, *bout, *Wmap, *bmap;
  float *PRE, *Wc, *bc, *h0buf, *h1buf, *embbuf, *PART;
  uint32_t *epochA, *epochB, *epochC;   // per-producer epoch words (no RMW anywhere)
  float *out;
};

__device__ __forceinline__ float bf_lo(uint32_t u){ return __uint_as_float(u << 16); }
__device__ __forceinline__ float bf_hi(uint32_t u){ return __uint_as_float(u & 0xffff0000u); }
__device__ __forceinline__ uint32_t packbf(float a, float b){
  uint32_t ua = __float_as_uint(a), ub = __float_as_uint(b);
  ua = (ua + 0x7fffu + ((ua >> 16) & 1u)) >> 16;           // RNE bf16 (low half)
  ub = (ub + 0x7fffu + ((ub >> 16) & 1u)) & 0xffff0000u;   // RNE bf16 (high half)
  return (ua & 0xffffu) | ub;
}
// Cross-block data: agent-scope relaxed atomics (write-through/read-through at the
// device coherence point; never stale). data->flag order: __syncthreads() drains
// vmcnt (stores acked) before the epoch store. No fences, no RMW in the loop.
__device__ __forceinline__ float gload(const float* p){
  return __hip_atomic_load(p, __ATOMIC_RELAXED, __HIP_MEMORY_SCOPE_AGENT);
}
__device__ __forceinline__ void gstore(float* p, float v){
  __hip_atomic_store(p, v, __ATOMIC_RELAXED, __HIP_MEMORY_SCOPE_AGENT);
}
__device__ __forceinline__ uint32_t gloadu(const uint32_t* p){
  return __hip_atomic_load(p, __ATOMIC_RELAXED, __HIP_MEMORY_SCOPE_AGENT);
}
__device__ __forceinline__ void gstoreu(uint32_t* p, uint32_t v){
  __hip_atomic_store(p, v, __ATOMIC_RELAXED, __HIP_MEMORY_SCOPE_AGENT);
}
__device__ __forceinline__ float sigm(float x){ return 1.f / (1.f + __expf(-x)); }

// ---------------- group A: LSTM layer 0 (96 blocks, 16 outputs each) ----------------
// wave w owns all 4 gates of output O=bid*16+w; lane k-map: k = l + 64j (packed pairs
// wr[g][p] = (k=l+128p, k=l+128p+64)). p=0..10 regs, p=11,12 LDS.
// Phase-1: p=0..11 (h0(t-1), self-barrier); phase-2: p=12 (emb(t-1), needs C).
__device__ __forceinline__ float asrc(const Params& P, int r, int k){
  if (k < HD) return P.Whh0[(size_t)r * HD + k];
  return P.Wih0[(size_t)r * (XDIM + EMBD) + XDIM + (k - HD)];
}
__device__ void run_A(const Params& P, int bid, uint32_t* smem){
  const int tid = threadIdx.x;
  const int w = tid >> 6, l = tid & 63;
  const int O = bid * 16 + w;
  float* xv = (float*)smem;            // 1664
  uint32_t* wlds = smem + 1664;        // 2*4*16*64 = 8192
  uint32_t wr[4][11];
#pragma unroll
  for (int g = 0; g < 4; ++g){
    int r = g * HD + O;
#pragma unroll
    for (int p = 0; p < 11; ++p)
      wr[g][p] = packbf(asrc(P, r, l + 128 * p), asrc(P, r, l + 128 * p + 64));
#pragma unroll
    for (int pp = 0; pp < 2; ++pp){
      int p = 11 + pp;
      wlds[((pp * 4 + g) * 16 + w) * 64 + l] =
          packbf(asrc(P, r, l + 128 * p), asrc(P, r, l + 128 * p + 64));
    }
  }
  float cst = P.c0in[O];
  int alive = 1;                        // meaningful in wave 0 only
  __syncthreads();
  for (int t = 0; t < T_STEPS; ++t){
    if (w == 0){                        // wait: all epochA >= t (self-barrier)
      uint32_t tgt = (uint32_t)t, n = 0;
      while (alive){
        uint32_t v0 = gloadu(P.epochA + l);
        uint32_t v1 = (l < 32) ? gloadu(P.epochA + 64 + l) : tgt;
        if (__all(v0 >= tgt && v1 >= tgt)) break;
        if (++n > 100000u) alive = 0;
      }
    }
    __syncthreads();
    const float* hp = P.h0buf + (((t & 1) ^ 1) * HD);
    xv[tid] = gload(hp + tid);
    if (tid < 512) xv[1024 + tid] = gload(hp + 1024 + tid);
    __syncthreads();
    float a0 = 0.f, a1 = 0.f, a2 = 0.f, a3 = 0.f;
#pragma unroll
    for (int p = 0; p < 11; ++p){
      float xa = xv[l + 128 * p], xb = xv[l + 128 * p + 64];
      uint32_t u0 = wr[0][p], u1 = wr[1][p], u2 = wr[2][p], u3 = wr[3][p];
      a0 += bf_lo(u0) * xa + bf_hi(u0) * xb;
      a1 += bf_lo(u1) * xa + bf_hi(u1) * xb;
      a2 += bf_lo(u2) * xa + bf_hi(u2) * xb;
      a3 += bf_lo(u3) * xa + bf_hi(u3) * xb;
    }
    {   // p=11 (LDS weights, h-part)
      float xa = xv[l + 1408], xb = xv[l + 1472];
      uint32_t u0 = wlds[((0) * 16 + w) * 64 + l];
      uint32_t u1 = wlds[((1) * 16 + w) * 64 + l];
      uint32_t u2 = wlds[((2) * 16 + w) * 64 + l];
      uint32_t u3 = wlds[((3) * 16 + w) * 64 + l];
      a0 += bf_lo(u0) * xa + bf_hi(u0) * xb;
      a1 += bf_lo(u1) * xa + bf_hi(u1) * xb;
      a2 += bf_lo(u2) * xa + bf_hi(u2) * xb;
      a3 += bf_lo(u3) * xa + bf_hi(u3) * xb;
    }
    if (w == 0){                        // wait: epochC >= t (emb(t-1) ready)
      uint32_t tgt = (uint32_t)t, n = 0;
      while (alive){
        uint32_t v = gloadu(P.epochC);
        if (__all(v >= tgt)) break;
        if (++n > 100000u) alive = 0;
      }
    }
    __syncthreads();
    if (tid < EMBD) xv[HD + tid] = gload(P.embbuf + (((t & 1) ^ 1) * EMBD) + tid);
    __syncthreads();
    {   // p=12 (LDS weights, emb-part)
      float xa = xv[l + 1536], xb = xv[l + 1600];
      uint32_t u0 = wlds[((4) * 16 + w) * 64 + l];
      uint32_t u1 = wlds[((5) * 16 + w) * 64 + l];
      uint32_t u2 = wlds[((6) * 16 + w) * 64 + l];
      uint32_t u3 = wlds[((7) * 16 + w) * 64 + l];
      a0 += bf_lo(u0) * xa + bf_hi(u0) * xb;
      a1 += bf_lo(u1) * xa + bf_hi(u1) * xb;
      a2 += bf_lo(u2) * xa + bf_hi(u2) * xb;
      a3 += bf_lo(u3) * xa + bf_hi(u3) * xb;
    }
#pragma unroll
    for (int m = 1; m < 64; m <<= 1){
      a0 += __shfl_xor(a0, m, 64);
      a1 += __shfl_xor(a1, m, 64);
      a2 += __shfl_xor(a2, m, 64);
      a3 += __shfl_xor(a3, m, 64);
    }
    const float* pre = P.PRE + (size_t)t * 6144;
    float gi = sigm(a0 + pre[O]);
    float gf = sigm(a1 + pre[HD + O]);
    float gg = tanhf(a2 + pre[2 * HD + O]);
    float go = sigm(a3 + pre[3 * HD + O]);
    cst = gf * cst + gi * gg;
    float hn = go * tanhf(cst);
    if (l == 0) gstore(P.h0buf + (t & 1) * HD + O, hn);
    __syncthreads();                    // drains vmcnt: h0 stores acked
    if (tid == 0) gstoreu(P.epochA + bid, (uint32_t)(t + 1));
  }
}

// ---------------- group B: LSTM layer 1 (128 blocks, 12 outputs each) ----------------
// 48 gate-rows; wave w owns rows idx=3w..3w+2 (idx=g*12+o). K=3072: p=0..11 -> h0(t),
// p=12..23 -> h1(t-1). Regs p=0..19 (60), LDS p=20..23 (48 KB).
// Phase-1 (p=12..23) needs only self-barrier; phase-2 (p=0..11) needs A@t (+C@t-1
// before the PART overwrite -- folded into the same wait).
__device__ __forceinline__ float bsrc(const Params& P, int r, int k){
  if (k < HD) return P.Wih1[(size_t)r * HD + k];
  return P.Whh1[(size_t)r * HD + (k - HD)];
}
__device__ void run_B(const Params& P, int bidb, uint32_t* smem){
  const int tid = threadIdx.x;
  const int w = tid >> 6, l = tid & 63;
  const int base = bidb * 12;
  float* xv = (float*)smem;             // 3072
  uint32_t* wlds = smem + 3072;         // 4*3*16*64 = 12288
  float* g1lds = (float*)(smem + 15360);  // 48
  float* c1lds = (float*)(smem + 15408);  // 12
  float* h1lds = (float*)(smem + 15420);  // 12
  uint32_t wr[3][20];
  float bias[3];
#pragma unroll
  for (int jj = 0; jj < 3; ++jj){
    int idx = 3 * w + jj;
    int g = idx / 12, o = idx % 12;
    int r = g * HD + base + o;
    bias[jj] = P.bih1[r] + P.bhh1[r];
#pragma unroll
    for (int p = 0; p < 20; ++p)
      wr[jj][p] = packbf(bsrc(P, r, l + 128 * p), bsrc(P, r, l + 128 * p + 64));
#pragma unroll
    for (int pp = 0; pp < 4; ++pp){
      int p = 20 + pp;
      wlds[((pp * 3 + jj) * 16 + w) * 64 + l] =
          packbf(bsrc(P, r, l + 128 * p), bsrc(P, r, l + 128 * p + 64));
    }
  }
  const int jrow = tid >> 2, cpart = tid & 3;
  float wc0 = 0.f, wc1 = 0.f, wc2 = 0.f;
  if (tid < 512){
    const float* wcp = P.Wc + (size_t)jrow * HD + base + cpart * 3;
    wc0 = wcp[0]; wc1 = wcp[1]; wc2 = wcp[2];
  }
  if (tid < 12) c1lds[tid] = P.c0in[HD + base + tid];
  int alive = 1;
  __syncthreads();
  for (int t = 0; t < T_STEPS; ++t){
    if (w == 0){                        // wait: all epochB >= t (self-barrier, h1/PART safety)
      uint32_t tgt = (uint32_t)t, n = 0;
      while (alive){
        uint32_t v0 = gloadu(P.epochB + l);
        uint32_t v1 = gloadu(P.epochB + 64 + l);
        if (__all(v0 >= tgt && v1 >= tgt)) break;
        if (++n > 100000u) alive = 0;
      }
    }
    __syncthreads();
    const float* h1p = P.h1buf + (((t & 1) ^ 1) * HD);
    xv[HD + tid] = gload(h1p + tid);
    if (tid < 512) xv[HD + 1024 + tid] = gload(h1p + 1024 + tid);
    __syncthreads();
    float a0 = 0.f, a1 = 0.f, a2 = 0.f;
#pragma unroll
    for (int p = 12; p < 20; ++p){      // h1-side, regs
      float xa = xv[l + 128 * p], xb = xv[l + 128 * p + 64];
      uint32_t u0 = wr[0][p], u1 = wr[1][p], u2 = wr[2][p];
      a0 += bf_lo(u0) * xa + bf_hi(u0) * xb;
      a1 += bf_lo(u1) * xa + bf_hi(u1) * xb;
      a2 += bf_lo(u2) * xa + bf_hi(u2) * xb;
    }
#pragma unroll
    for (int pp = 0; pp < 4; ++pp){     // h1-side, LDS weights
      int p = 20 + pp;
      float xa = xv[l + 128 * p], xb = xv[l + 128 * p + 64];
      uint32_t u0 = wlds[((pp * 3 + 0) * 16 + w) * 64 + l];
      uint32_t u1 = wlds[((pp * 3 + 1) * 16 + w) * 64 + l];
      uint32_t u2 = wlds[((pp * 3 + 2) * 16 + w) * 64 + l];
      a0 += bf_lo(u0) * xa + bf_hi(u0) * xb;
      a1 += bf_lo(u1) * xa + bf_hi(u1) * xb;
      a2 += bf_lo(u2) * xa + bf_hi(u2) * xb;
    }
    if (w == 0){   // wait: all epochA >= t+1 (h0(t) ready) AND epochC >= t (PART(t-1) consumed)
      uint32_t tgt = (uint32_t)(t + 1), tgc = (uint32_t)t, n = 0;
      while (alive){
        uint32_t v0 = gloadu(P.epochA + l);
        uint32_t v1 = (l < 32) ? gloadu(P.epochA + 64 + l) : tgt;
        uint32_t v2 = gloadu(P.epochC);
        if (__all(v0 >= tgt && v1 >= tgt && v2 >= tgc)) break;
        if (++n > 100000u) alive = 0;
      }
    }
    __syncthreads();
    const float* h0p = P.h0buf + (t & 1) * HD;
    xv[tid] = gload(h0p + tid);
    if (tid < 512) xv[1024 + tid] = gload(h0p + 1024 + tid);
    __syncthreads();
#pragma unroll
    for (int p = 0; p < 12; ++p){       // h0-side, regs
      float xa = xv[l + 128 * p], xb = xv[l + 128 * p + 64];
      uint32_t u0 = wr[0][p], u1 = wr[1][p], u2 = wr[2][p];
      a0 += bf_lo(u0) * xa + bf_hi(u0) * xb;
      a1 += bf_lo(u1) * xa + bf_hi(u1) * xb;
      a2 += bf_lo(u2) * xa + bf_hi(u2) * xb;
    }
#pragma unroll
    for (int m = 1; m < 64; m <<= 1){
      a0 += __shfl_xor(a0, m, 64);
      a1 += __shfl_xor(a1, m, 64);
      a2 += __shfl_xor(a2, m, 64);
    }
    if (l == 0){
      g1lds[3 * w + 0] = a0 + bias[0];
      g1lds[3 * w + 1] = a1 + bias[1];
      g1lds[3 * w + 2] = a2 + bias[2];
    }
    __syncthreads();
    if (tid < 12){
      int o = tid;
      float gi = sigm(g1lds[o]);
      float gf = sigm(g1lds[12 + o]);
      float gg = tanhf(g1lds[24 + o]);
      float go = sigm(g1lds[36 + o]);
      float c = gf * c1lds[o] + gi * gg;
      c1lds[o] = c;
      float hn = go * tanhf(c);
      h1lds[o] = hn;
      gstore(P.h1buf + (t & 1) * HD + base + o, hn);
    }
    __syncthreads();
    if (tid < 512){
      float pp = wc0 * h1lds[cpart * 3] + wc1 * h1lds[cpart * 3 + 1] + wc2 * h1lds[cpart * 3 + 2];
      pp += __shfl_xor(pp, 1, 64);
      pp += __shfl_xor(pp, 2, 64);
      if (cpart == 0) gstore(P.PART + bidb * 128 + jrow, pp);
    }
    __syncthreads();                    // drains vmcnt: h1 + PART stores acked
    if (tid == 0) gstoreu(P.epochB + bidb, (uint32_t)(t + 1));
  }
}

// ---------------- group C: logit-sum + softmax + out + emb (1 block) ----------------
__device__ void run_C(const Params& P, uint32_t* smem){
  const int tid = threadIdx.x;
  float* partred = (float*)smem;          // 1024
  float* lg   = (float*)(smem + 1024);    // 128
  float* plds = (float*)(smem + 1152);    // 128
  float* bcs  = (float*)(smem + 1280);    // 128
  float* red2 = (float*)(smem + 1408);    // 2
  float wm[16];
  const int e = tid >> 3, jc = tid & 7;
#pragma unroll
  for (int i = 0; i < 16; ++i) wm[i] = P.Wmap[(size_t)e * 128 + jc * 16 + i];
  float bm = P.bmap[e];
  if (tid < 128) bcs[tid] = P.bc[tid];
  int alive = 1;
  const int w = tid >> 6, l = tid & 63;
  __syncthreads();
  for (int t = 0; t < T_STEPS; ++t){
    if (w == 0){                        // wait: all epochB >= t+1
      uint32_t tgt = (uint32_t)(t + 1), n = 0;
      while (alive){
        uint32_t v0 = gloadu(P.epochB + l);
        uint32_t v1 = gloadu(P.epochB + 64 + l);
        if (__all(v0 >= tgt && v1 >= tgt)) break;
        if (++n > 100000u) alive = 0;
      }
    }
    __syncthreads();
    const int j = tid & 127, b8 = tid >> 7;
    float s = 0.f;
#pragma unroll
    for (int i = 0; i < 16; ++i) s += gload(P.PART + (b8 * 16 + i) * 128 + j);
    partred[b8 * 128 + j] = s;
    __syncthreads();
    if (tid < 128){
      float lt = bcs[tid];
#pragma unroll
      for (int i = 0; i < 8; ++i) lt += partred[i * 128 + tid];
      lg[tid] = lt;
    }
    __syncthreads();
    if (tid < 64){
      float m = fmaxf(lg[tid], lg[tid + 64]);
#pragma unroll
      for (int k = 1; k < 64; k <<= 1) m = fmaxf(m, __shfl_xor(m, k, 64));
      float sd = __expf(lg[tid] - m) + __expf(lg[tid + 64] - m);
#pragma unroll
      for (int k = 1; k < 64; k <<= 1) sd += __shfl_xor(sd, k, 64);
      if (tid == 0){ red2[0] = m; red2[1] = 1.f / sd; }
    }
    __syncthreads();
    if (tid < 128){
      float pv = __expf(lg[tid] - red2[0]) * red2[1];
      plds[tid] = pv;
      P.out[(size_t)t * 128 + tid] = pv;   // host-only consumer: plain store ok
    }
    __syncthreads();
    float a = 0.f;
#pragma unroll
    for (int i = 0; i < 16; ++i) a += wm[i] * plds[jc * 16 + i];
    a += __shfl_xor(a, 1, 64);
    a += __shfl_xor(a, 2, 64);
    a += __shfl_xor(a, 4, 64);
    if (jc == 0) gstore(P.embbuf + (t & 1) * EMBD + e, a + bm);
    __syncthreads();                    // drains vmcnt: emb stores acked
    if (tid == 0) gstoreu(P.epochC, (uint32_t)(t + 1));
  }
}

// amdgpu_waves_per_eu(4,4): raw clang attr -> 128-VGPR budget (round 2's
// __launch_bounds__(1024,4) left the budget at 64 -> weight spill -> 37.5 GB
// of per-step reload traffic). LDS carve is a manual union: per-role static
// arrays SUM on this compiler (round-2 LDS_Block_Size = 25 KB = sum).
__global__ __launch_bounds__(1024) __attribute__((amdgpu_waves_per_eu(4, 4)))
void k_lstm(Params P){
  __shared__ __align__(16) uint32_t smem[15436];   // 61.7 KB, max over roles (B)
  int bid = blockIdx.x;
  if (bid < NA) run_A(P, bid, smem);
  else if (bid < NA + NB) run_B(P, bid - NA, smem);
  else run_C(P, smem);
}

// ---------------- pre-kernels ----------------
__global__ void k_init(const float* h0in, float* h0buf, float* h1buf, float* embbuf,
                       uint32_t* epochs){
  int tid = threadIdx.x;
  for (int i = tid; i < HD; i += 256){
    float a = h0in[i], b = h0in[HD + i];
    h0buf[i] = a; h0buf[HD + i] = a;
    h1buf[i] = b; h1buf[HD + i] = b;
  }
  if (tid < 128){ embbuf[tid] = 0.f; embbuf[128 + tid] = 0.f; }
  for (int i = tid; i < 320; i += 256) epochs[i] = 0u;
}

// PRE[t][r] = b_ih0[r]+b_hh0[r] + sum_{k<118} W_ih0[r][k]*x[t][k]
__global__ void k_pre(const float* x, const float* Wih0, const float* bih0, const float* bhh0, float* PRE){
  int tb = blockIdx.x >> 2;
  int rc = blockIdx.x & 3;
  int tid = threadIdx.x;
  __shared__ float xl[32 * XDIM];
  for (int i = tid; i < 32 * XDIM; i += 256){
    int tt = i / XDIM, k = i % XDIM;
    xl[i] = x[(size_t)(tb * 32 + tt) * XDIM + k];
  }
  __syncthreads();
  for (int rr = 0; rr < 6; ++rr){
    int r = rc * HD + rr * 256 + tid;
    float acc[32];
#pragma unroll
    for (int t = 0; t < 32; ++t) acc[t] = 0.f;
    const float* wrow = Wih0 + (size_t)r * (XDIM + EMBD);
    for (int k = 0; k < XDIM; ++k){
      float wv = wrow[k];
#pragma unroll
      for (int t = 0; t < 32; ++t) acc[t] += wv * xl[t * XDIM + k];
    }
    float bb = bih0[r] + bhh0[r];
    for (int t = 0; t < 32; ++t)
      PRE[(size_t)(tb * 32 + t) * 6144 + r] = acc[t] + bb;
  }
}

// Wc = W_out @ W_hl (128x1536, K=1024); bc = W_out @ b_hl + b_out
__global__ void k_wc(const float* Whl, const float* Wout, const float* bhl, const float* bout,
                     float* Wc, float* bc){
  if (blockIdx.x == 96){
    int j = threadIdx.x;
    if (j < 128){
      float a = 0.f;
      for (int m = 0; m < 1024; ++m) a += Wout[(size_t)j * 1024 + m] * bhl[m];
      bc[j] = a + bout[j];
    }
    return;
  }
  int kt = blockIdx.x % 6, jt = blockIdx.x / 6;
  __shared__ float wo[8 * 1024];
  int tid = threadIdx.x;
  for (int i = tid; i < 8 * 1024; i += 256) wo[i] = Wout[(size_t)(jt * 8) * 1024 + i];
  __syncthreads();
  int k = kt * 256 + tid;
  float acc[8];
#pragma unroll
  for (int jj = 0; jj < 8; ++jj) acc[jj] = 0.f;
  for (int m = 0; m < 1024; ++m){
    float wl = Whl[(size_t)m * HD + k];
#pragma unroll
    for (int jj = 0; jj < 8; ++jj) acc[jj] += wo[jj * 1024 + m] * wl;
  }
#pragma unroll
  for (int jj = 0; jj < 8; ++jj) Wc[(size_t)(jt * 8 + jj) * HD + k] = acc[jj];
}

__global__ void k_sentinel(float* out){ out[0] = 1.0e6f; }

extern "C" void kernel_launch(void* const* d_in, const int* in_sizes, int n_in,
                              void* d_out, int out_size, void* d_ws, size_t ws_size,
                              hipStream_t stream){
  (void)in_sizes; (void)n_in; (void)out_size;
  const float* x    = (const float*)d_in[0];
  const float* h0in = (const float*)d_in[1];
  const float* c0in = (const float*)d_in[2];
  const float* Wih0 = (const float*)d_in[3];
  const float* Whh0 = (const float*)d_in[4];
  const float* bih0 = (const float*)d_in[5];
  const float* bhh0 = (const float*)d_in[6];
  const float* Wih1 = (const float*)d_in[7];
  const float* Whh1 = (const float*)d_in[8];
  const float* bih1 = (const float*)d_in[9];
  const float* bhh1 = (const float*)d_in[10];
  const float* Whl  = (const float*)d_in[11];
  const float* bhl  = (const float*)d_in[12];
  const float* Wout = (const float*)d_in[13];
  const float* bout = (const float*)d_in[14];
  const float* Wmap = (const float*)d_in[15];
  const float* bmap = (const float*)d_in[16];
  float* out = (float*)d_out;
  float* ws = (float*)d_ws;

  size_t off = 0;
  float* PRE    = ws + off; off += (size_t)T_STEPS * 6144;
  float* Wc     = ws + off; off += 128 * HD;
  float* bc     = ws + off; off += 128;
  float* h0buf  = ws + off; off += 2 * HD;
  float* h1buf  = ws + off; off += 2 * HD;
  float* embbuf = ws + off; off += 2 * EMBD;
  float* PART   = ws + off; off += 128 * 128;
  off = (off + 63) & ~(size_t)63;
  uint32_t* epochs = (uint32_t*)(ws + off); off += 320;   // A[0..127], B[128..255], C[256]

  if (ws_size < off * sizeof(float) + 1024){
    hipLaunchKernelGGL(k_sentinel, dim3(1), dim3(1), 0, stream, out);
    return;
  }

  hipLaunchKernelGGL(k_init, dim3(1), dim3(256), 0, stream, h0in, h0buf, h1buf, embbuf, epochs);
  hipLaunchKernelGGL(k_pre, dim3(256), dim3(256), 0, stream, x, Wih0, bih0, bhh0, PRE);
  hipLaunchKernelGGL(k_wc, dim3(97), dim3(256), 0, stream, Whl, Wout, bhl, bout, Wc, bc);

  Params P;
  P.x = x; P.h0in = h0in; P.c0in = c0in;
  P.Wih0 = Wih0; P.Whh0 = Whh0; P.bih0 = bih0; P.bhh0 = bhh0;
  P.Wih1 = Wih1; P.Whh1 = Whh1; P.bih1 = bih1; P.bhh1 = bhh1;
  P.Whl = Whl; P.bhl = bhl; P.Wout = Wout; P.bout = bout; P.Wmap = Wmap; P.bmap = bmap;
  P.PRE = PRE; P.Wc = Wc; P.bc = bc;
  P.h0buf = h0buf; P.h1buf = h1buf; P.embbuf = embbuf; P.PART = PART;
  P.epochA = epochs; P.epochB = epochs + 128; P.epochC = epochs + 256;
  P.out = out;

  hipLaunchKernelGGL(k_lstm, dim3(NBLK), dim3(1024), 0, stream, P);
}

// Round 4
// 30626.498 us; speedup vs baseline: 14.8526x; 1.9051x over previous
//
#include <hip/hip_runtime.h>
#include <math.h>
#include <stdint.h>

#define T_STEPS 2048
#define XDIM 118
#define EMBD 128
#define HD 1536
#define NA 96
#define NB 128
#define NBLK (NA + NB + 1)

// epoch word layout (uint32 indices into P.ep): separate 64B lines for hot words
#define EP_A   0     // epochA[0..95]
#define EP_B   128   // epochB[0..127]
#define EP_C   256   // epochC (single word)
#define EP_AG  288   // epochAagg (single word, published by B0)
#define EP_N   320

// dynamic LDS: B needs 12288 (xv) + 147456 (weights) + 288 (small) = 160032 B
#define SMEM_BYTES 160032

struct Params {
  const float *x, *h0in, *c0in;
  const float *Wih0, *Whh0, *bih0, *bhh0;
  const float *Wih1, *Whh1, *bih1, *bhh1;
  const float *Whl, *bhl, *Wout, *bout, *Wmap, *bmap;
  float *PRE, *Wc, *bc, *h0buf, *h1buf, *embbuf, *PART;
  uint32_t *ep;
  float *out;
};

__device__ __forceinline__ float bf_lo(uint32_t u){ return __uint_as_float(u << 16); }
__device__ __forceinline__ float bf_hi(uint32_t u){ return __uint_as_float(u & 0xffff0000u); }
__device__ __forceinline__ uint32_t packbf(float a, float b){
  uint32_t ua = __float_as_uint(a), ub = __float_as_uint(b);
  ua = (ua + 0x7fffu + ((ua >> 16) & 1u)) >> 16;           // RNE bf16 (low half)
  ub = (ub + 0x7fffu + ((ub >> 16) & 1u)) & 0xffff0000u;   // RNE bf16 (high half)
  return (ua & 0xffffu) | ub;
}
// Cross-block data via agent-scope relaxed atomics (read/write at the device
// coherence point -> never stale). data->flag ordering: __syncthreads() drains
// vmcnt (stores acked) before the epoch store. No fences, no RMW in the loop.
__device__ __forceinline__ float gload(const float* p){
  return __hip_atomic_load(p, __ATOMIC_RELAXED, __HIP_MEMORY_SCOPE_AGENT);
}
__device__ __forceinline__ void gstore(float* p, float v){
  __hip_atomic_store(p, v, __ATOMIC_RELAXED, __HIP_MEMORY_SCOPE_AGENT);
}
__device__ __forceinline__ uint32_t gloadu(const uint32_t* p){
  return __hip_atomic_load(p, __ATOMIC_RELAXED, __HIP_MEMORY_SCOPE_AGENT);
}
__device__ __forceinline__ void gstoreu(uint32_t* p, uint32_t v){
  __hip_atomic_store(p, v, __ATOMIC_RELAXED, __HIP_MEMORY_SCOPE_AGENT);
}
__device__ __forceinline__ float sigm(float x){ return 1.f / (1.f + __expf(-x)); }

// ---------------- group A: LSTM layer 0 (96 blocks, 16 outputs each) ----------------
// wave w owns all 4 gates of output O=bid*16+w. K=1664 in 13 slots of 128;
// slot p covers k = 128p + 2l, +1 (adjacent pairs -> contiguous b64 LDS reads).
// Regs: p=0..7 (h0) + p=12 (emb). LDS: p=8..11 (h0).
// Waits: phase-1 <- epochAagg>=t (1 word); phase-2 <- epochC>=t (1 word).
__device__ __forceinline__ float asrc(const Params& P, int r, int k){
  if (k < HD) return P.Whh0[(size_t)r * HD + k];
  return P.Wih0[(size_t)r * (XDIM + EMBD) + XDIM + (k - HD)];
}
__device__ void run_A(const Params& P, int bid, uint32_t* smem){
  const int tid = threadIdx.x;
  const int w = tid >> 6, l = tid & 63;
  const int O = bid * 16 + w;
  float* xv = (float*)smem;                 // 1664 floats
  uint2* wl2 = (uint2*)(smem + 1664);       // 2*4*1024 uint2 = 64 KB
  uint32_t wr[4][8];
  uint32_t wremb[4];
#pragma unroll
  for (int g = 0; g < 4; ++g){
    int r = g * HD + O;
#pragma unroll
    for (int p = 0; p < 8; ++p)
      wr[g][p] = packbf(asrc(P, r, 128 * p + 2 * l), asrc(P, r, 128 * p + 2 * l + 1));
#pragma unroll
    for (int q = 0; q < 2; ++q){
      uint2 u;
      u.x = packbf(asrc(P, r, 128 * (8 + 2 * q) + 2 * l), asrc(P, r, 128 * (8 + 2 * q) + 2 * l + 1));
      u.y = packbf(asrc(P, r, 128 * (9 + 2 * q) + 2 * l), asrc(P, r, 128 * (9 + 2 * q) + 2 * l + 1));
      wl2[(q * 4 + g) * 1024 + tid] = u;
    }
    wremb[g] = packbf(asrc(P, r, 1536 + 2 * l), asrc(P, r, 1537 + 2 * l));
  }
  float cst = P.c0in[O];
  int alive = 1;                             // wave-0 lanes only
  __syncthreads();
  for (int t = 0; t < T_STEPS; ++t){
    const float* pre = P.PRE + (size_t)t * 6144;     // prefetch early (plain loads)
    float q0 = pre[O], q1 = pre[HD + O], q2 = pre[2 * HD + O], q3 = pre[3 * HD + O];
    if (w == 0 && alive){                    // all epochA >= t (via B0's aggregate)
      uint32_t n = 0;
      while (gloadu(P.ep + EP_AG) < (uint32_t)t){
        if (++n > 5000000u){ alive = 0; break; }
      }
    }
    __syncthreads();
    const float* hp = P.h0buf + (((t & 1) ^ 1) * HD);
    xv[tid] = gload(hp + tid);
    if (tid < 512) xv[1024 + tid] = gload(hp + 1024 + tid);
    __syncthreads();
    float a0 = 0.f, a1 = 0.f, a2 = 0.f, a3 = 0.f;
#pragma unroll
    for (int p = 0; p < 8; ++p){
      float2 x2 = *(const float2*)&xv[128 * p + 2 * l];
      uint32_t u0 = wr[0][p], u1 = wr[1][p], u2 = wr[2][p], u3 = wr[3][p];
      a0 += bf_lo(u0) * x2.x + bf_hi(u0) * x2.y;
      a1 += bf_lo(u1) * x2.x + bf_hi(u1) * x2.y;
      a2 += bf_lo(u2) * x2.x + bf_hi(u2) * x2.y;
      a3 += bf_lo(u3) * x2.x + bf_hi(u3) * x2.y;
    }
#pragma unroll
    for (int q = 0; q < 2; ++q){
      float2 xa = *(const float2*)&xv[128 * (8 + 2 * q) + 2 * l];
      float2 xb = *(const float2*)&xv[128 * (9 + 2 * q) + 2 * l];
      uint2 u0 = wl2[(q * 4 + 0) * 1024 + tid];
      uint2 u1 = wl2[(q * 4 + 1) * 1024 + tid];
      uint2 u2 = wl2[(q * 4 + 2) * 1024 + tid];
      uint2 u3 = wl2[(q * 4 + 3) * 1024 + tid];
      a0 += bf_lo(u0.x) * xa.x + bf_hi(u0.x) * xa.y + bf_lo(u0.y) * xb.x + bf_hi(u0.y) * xb.y;
      a1 += bf_lo(u1.x) * xa.x + bf_hi(u1.x) * xa.y + bf_lo(u1.y) * xb.x + bf_hi(u1.y) * xb.y;
      a2 += bf_lo(u2.x) * xa.x + bf_hi(u2.x) * xa.y + bf_lo(u2.y) * xb.x + bf_hi(u2.y) * xb.y;
      a3 += bf_lo(u3.x) * xa.x + bf_hi(u3.x) * xa.y + bf_lo(u3.y) * xb.x + bf_hi(u3.y) * xb.y;
    }
    if (w == 0 && alive){                    // emb(t-1) ready
      uint32_t n = 0;
      while (gloadu(P.ep + EP_C) < (uint32_t)t){
        if (++n > 5000000u){ alive = 0; break; }
      }
    }
    __syncthreads();
    if (tid < EMBD) xv[HD + tid] = gload(P.embbuf + (((t & 1) ^ 1) * EMBD) + tid);
    __syncthreads();
    {
      float2 x2 = *(const float2*)&xv[1536 + 2 * l];
      a0 += bf_lo(wremb[0]) * x2.x + bf_hi(wremb[0]) * x2.y;
      a1 += bf_lo(wremb[1]) * x2.x + bf_hi(wremb[1]) * x2.y;
      a2 += bf_lo(wremb[2]) * x2.x + bf_hi(wremb[2]) * x2.y;
      a3 += bf_lo(wremb[3]) * x2.x + bf_hi(wremb[3]) * x2.y;
    }
#pragma unroll
    for (int m = 1; m < 64; m <<= 1){
      a0 += __shfl_xor(a0, m, 64);
      a1 += __shfl_xor(a1, m, 64);
      a2 += __shfl_xor(a2, m, 64);
      a3 += __shfl_xor(a3, m, 64);
    }
    float gi = sigm(a0 + q0);
    float gf = sigm(a1 + q1);
    float gg = tanhf(a2 + q2);
    float go = sigm(a3 + q3);
    cst = gf * cst + gi * gg;
    float hn = go * tanhf(cst);
    if (l == 0) gstore(P.h0buf + (t & 1) * HD + O, hn);
    __syncthreads();                         // drains vmcnt: h0 stores acked
    if (tid == 0) gstoreu(P.ep + EP_A + bid, (uint32_t)(t + 1));
  }
}

// ---------------- group B: LSTM layer 1 (128 blocks, 12 outputs each) ----------------
// 48 gate-rows; wave w owns rows idx=3w+jj (idx=g*12+o). K=3072 in 24 slots;
// slot p: k = 128p+2l,+1.  p=0..11 -> h0(t) [REGS, serial phase-2];
// p=12..23 -> h1(t-1) [LDS, phase-1, overlapped].
// Waits: phase-1 <- epochC>=t (1 word; implies all epochB>=t and PART(t-1)
// consumed); phase-2 <- epochAagg>=t+1 (B0 polls raw epochA and publishes).
__device__ __forceinline__ float bsrc(const Params& P, int r, int k){
  if (k < HD) return P.Wih1[(size_t)r * HD + k];
  return P.Whh1[(size_t)r * HD + (k - HD)];
}
__device__ void run_B(const Params& P, int bidb, uint32_t* smem){
  const int tid = threadIdx.x;
  const int w = tid >> 6, l = tid & 63;
  const int base = bidb * 12;
  float* xv = (float*)smem;                  // 3072 floats = 12288 B
  uint2* wl2 = (uint2*)(smem + 3072);        // 6*3*1024 uint2 = 147456 B
  float* g1lds = (float*)(smem + 39936);     // 48
  float* c1lds = g1lds + 48;                 // 12
  float* h1lds = c1lds + 12;                 // 12
  uint32_t wr[3][12];
  float bias[3];
#pragma unroll
  for (int jj = 0; jj < 3; ++jj){
    int idx = 3 * w + jj;
    int g = idx / 12, o = idx % 12;
    int r = g * HD + base + o;
    bias[jj] = P.bih1[r] + P.bhh1[r];
#pragma unroll
    for (int p = 0; p < 12; ++p)
      wr[jj][p] = packbf(bsrc(P, r, 128 * p + 2 * l), bsrc(P, r, 128 * p + 2 * l + 1));
#pragma unroll
    for (int q = 0; q < 6; ++q){
      uint2 u;
      u.x = packbf(bsrc(P, r, 128 * (12 + 2 * q) + 2 * l), bsrc(P, r, 128 * (12 + 2 * q) + 2 * l + 1));
      u.y = packbf(bsrc(P, r, 128 * (13 + 2 * q) + 2 * l), bsrc(P, r, 128 * (13 + 2 * q) + 2 * l + 1));
      wl2[(q * 3 + jj) * 1024 + tid] = u;
    }
  }
  const int jrow = tid >> 2, cpart = tid & 3;
  float wc0 = 0.f, wc1 = 0.f, wc2 = 0.f;
  if (tid < 512){
    const float* wcp = P.Wc + (size_t)jrow * HD + base + cpart * 3;
    wc0 = wcp[0]; wc1 = wcp[1]; wc2 = wcp[2];
  }
  if (tid < 12) c1lds[tid] = P.c0in[HD + base + tid];
  int alive = 1;
  __syncthreads();
  for (int t = 0; t < T_STEPS; ++t){
    if (w == 0 && alive){                    // epochC>=t: h1(t-1)/PART safety + emb chain
      uint32_t n = 0;
      while (gloadu(P.ep + EP_C) < (uint32_t)t){
        if (++n > 5000000u){ alive = 0; break; }
      }
    }
    __syncthreads();
    const float* h1p = P.h1buf + (((t & 1) ^ 1) * HD);
    xv[1536 + tid] = gload(h1p + tid);
    if (tid < 512) xv[2560 + tid] = gload(h1p + 1024 + tid);
    __syncthreads();
    float a0 = 0.f, a1 = 0.f, a2 = 0.f;
#pragma unroll
    for (int q = 0; q < 6; ++q){             // h1 side (LDS weights) — overlapped phase
      float2 xa = *(const float2*)&xv[128 * (12 + 2 * q) + 2 * l];
      float2 xb = *(const float2*)&xv[128 * (13 + 2 * q) + 2 * l];
      uint2 u0 = wl2[(q * 3 + 0) * 1024 + tid];
      uint2 u1 = wl2[(q * 3 + 1) * 1024 + tid];
      uint2 u2 = wl2[(q * 3 + 2) * 1024 + tid];
      a0 += bf_lo(u0.x) * xa.x + bf_hi(u0.x) * xa.y + bf_lo(u0.y) * xb.x + bf_hi(u0.y) * xb.y;
      a1 += bf_lo(u1.x) * xa.x + bf_hi(u1.x) * xa.y + bf_lo(u1.y) * xb.x + bf_hi(u1.y) * xb.y;
      a2 += bf_lo(u2.x) * xa.x + bf_hi(u2.x) * xa.y + bf_lo(u2.y) * xb.x + bf_hi(u2.y) * xb.y;
    }
    if (w == 0 && alive){                    // h0(t) ready
      uint32_t tgt = (uint32_t)(t + 1), n = 0;
      if (bidb == 0){                        // B0: sole wide poller, publishes aggregate
        while (1){
          uint32_t v0 = gloadu(P.ep + EP_A + l);
          uint32_t v1 = (l < 32) ? gloadu(P.ep + EP_A + 64 + l) : tgt;
          if (__all(v0 >= tgt && v1 >= tgt)) break;
          if (++n > 5000000u){ alive = 0; break; }
        }
        if (l == 0 && alive) gstoreu(P.ep + EP_AG, tgt);
      } else {
        while (gloadu(P.ep + EP_AG) < tgt){
          if (++n > 5000000u){ alive = 0; break; }
        }
      }
    }
    __syncthreads();
    const float* h0p = P.h0buf + (t & 1) * HD;
    xv[tid] = gload(h0p + tid);
    if (tid < 512) xv[1024 + tid] = gload(h0p + 1024 + tid);
    __syncthreads();
#pragma unroll
    for (int p = 0; p < 12; ++p){            // h0 side (reg weights) — serial phase
      float2 x2 = *(const float2*)&xv[128 * p + 2 * l];
      uint32_t u0 = wr[0][p], u1 = wr[1][p], u2 = wr[2][p];
      a0 += bf_lo(u0) * x2.x + bf_hi(u0) * x2.y;
      a1 += bf_lo(u1) * x2.x + bf_hi(u1) * x2.y;
      a2 += bf_lo(u2) * x2.x + bf_hi(u2) * x2.y;
    }
#pragma unroll
    for (int m = 1; m < 64; m <<= 1){
      a0 += __shfl_xor(a0, m, 64);
      a1 += __shfl_xor(a1, m, 64);
      a2 += __shfl_xor(a2, m, 64);
    }
    if (l == 0){
      g1lds[3 * w + 0] = a0 + bias[0];
      g1lds[3 * w + 1] = a1 + bias[1];
      g1lds[3 * w + 2] = a2 + bias[2];
    }
    __syncthreads();
    if (tid < 12){
      int o = tid;
      float gi = sigm(g1lds[o]);
      float gf = sigm(g1lds[12 + o]);
      float gg = tanhf(g1lds[24 + o]);
      float go = sigm(g1lds[36 + o]);
      float c = gf * c1lds[o] + gi * gg;
      c1lds[o] = c;
      float hn = go * tanhf(c);
      h1lds[o] = hn;
      gstore(P.h1buf + (t & 1) * HD + base + o, hn);
    }
    __syncthreads();
    if (tid < 512){
      float pp = wc0 * h1lds[cpart * 3] + wc1 * h1lds[cpart * 3 + 1] + wc2 * h1lds[cpart * 3 + 2];
      pp += __shfl_xor(pp, 1, 64);
      pp += __shfl_xor(pp, 2, 64);
      if (cpart == 0) gstore(P.PART + bidb * 128 + jrow, pp);
    }
    __syncthreads();                         // drains vmcnt: h1 + PART acked
    if (tid == 0) gstoreu(P.ep + EP_B + bidb, (uint32_t)(t + 1));
  }
}

// ---------------- group C: logit-sum + softmax + out + emb (1 block) ----------------
__device__ void run_C(const Params& P, uint32_t* smem){
  const int tid = threadIdx.x;
  float* partred = (float*)smem;             // 1024
  float* lg   = (float*)(smem + 1024);       // 128
  float* plds = (float*)(smem + 1152);       // 128
  float* bcs  = (float*)(smem + 1280);       // 128
  float* red2 = (float*)(smem + 1408);       // 2
  float wm[16];
  const int e = tid >> 3, jc = tid & 7;
#pragma unroll
  for (int i = 0; i < 16; ++i) wm[i] = P.Wmap[(size_t)e * 128 + jc * 16 + i];
  float bm = P.bmap[e];
  if (tid < 128) bcs[tid] = P.bc[tid];
  int alive = 1;
  const int w = tid >> 6, l = tid & 63;
  __syncthreads();
  for (int t = 0; t < T_STEPS; ++t){
    if (w == 0 && alive){                    // sole wide poller of epochB
      uint32_t tgt = (uint32_t)(t + 1), n = 0;
      while (1){
        uint32_t v0 = gloadu(P.ep + EP_B + l);
        uint32_t v1 = gloadu(P.ep + EP_B + 64 + l);
        if (__all(v0 >= tgt && v1 >= tgt)) break;
        if (++n > 5000000u){ alive = 0; break; }
      }
    }
    __syncthreads();
    const int j = tid & 127, b8 = tid >> 7;
    float s = 0.f;
#pragma unroll
    for (int i = 0; i < 16; ++i) s += gload(P.PART + (b8 * 16 + i) * 128 + j);
    partred[b8 * 128 + j] = s;
    __syncthreads();
    if (tid < 128){
      float lt = bcs[tid];
#pragma unroll
      for (int i = 0; i < 8; ++i) lt += partred[i * 128 + tid];
      lg[tid] = lt;
    }
    __syncthreads();
    if (tid < 64){
      float m = fmaxf(lg[tid], lg[tid + 64]);
#pragma unroll
      for (int k = 1; k < 64; k <<= 1) m = fmaxf(m, __shfl_xor(m, k, 64));
      float sd = __expf(lg[tid] - m) + __expf(lg[tid + 64] - m);
#pragma unroll
      for (int k = 1; k < 64; k <<= 1) sd += __shfl_xor(sd, k, 64);
      if (tid == 0){ red2[0] = m; red2[1] = 1.f / sd; }
    }
    __syncthreads();
    if (tid < 128){
      float pv = __expf(lg[tid] - red2[0]) * red2[1];
      plds[tid] = pv;
      P.out[(size_t)t * 128 + tid] = pv;     // host-only consumer: plain store ok
    }
    __syncthreads();
    float a = 0.f;
#pragma unroll
    for (int i = 0; i < 16; ++i) a += wm[i] * plds[jc * 16 + i];
    a += __shfl_xor(a, 1, 64);
    a += __shfl_xor(a, 2, 64);
    a += __shfl_xor(a, 4, 64);
    if (jc == 0) gstore(P.embbuf + (t & 1) * EMBD + e, a + bm);
    __syncthreads();                         // drains vmcnt: emb acked
    if (tid == 0) gstoreu(P.ep + EP_C, (uint32_t)(t + 1));
  }
}

// Per-thread VGPR demand designed to fit the observed 64-reg budget (two attribute
// mechanisms failed to raise it; spills cost ~13 GB/run). Bulk weights live in
// dynamic LDS (160 KB/CU) instead.
__global__ __launch_bounds__(1024) void k_lstm(Params P){
  extern __shared__ __align__(16) uint32_t smem[];
  int bid = blockIdx.x;
  if (bid < NA) run_A(P, bid, smem);
  else if (bid < NA + NB) run_B(P, bid - NA, smem);
  else run_C(P, smem);
}

// ---------------- pre-kernels ----------------
__global__ void k_init(const float* h0in, float* h0buf, float* h1buf, float* embbuf,
                       uint32_t* ep){
  int tid = threadIdx.x;
  for (int i = tid; i < HD; i += 256){
    float a = h0in[i], b = h0in[HD + i];
    h0buf[i] = a; h0buf[HD + i] = a;
    h1buf[i] = b; h1buf[HD + i] = b;
  }
  if (tid < 128){ embbuf[tid] = 0.f; embbuf[128 + tid] = 0.f; }
  for (int i = tid; i < EP_N; i += 256) ep[i] = 0u;
}

// PRE[t][r] = b_ih0[r]+b_hh0[r] + sum_{k<118} W_ih0[r][k]*x[t][k]
__global__ void k_pre(const float* x, const float* Wih0, const float* bih0, const float* bhh0, float* PRE){
  int tb = blockIdx.x >> 2;
  int rc = blockIdx.x & 3;
  int tid = threadIdx.x;
  __shared__ float xl[32 * XDIM];
  for (int i = tid; i < 32 * XDIM; i += 256){
    int tt = i / XDIM, k = i % XDIM;
    xl[i] = x[(size_t)(tb * 32 + tt) * XDIM + k];
  }
  __syncthreads();
  for (int rr = 0; rr < 6; ++rr){
    int r = rc * HD + rr * 256 + tid;
    float acc[32];
#pragma unroll
    for (int t = 0; t < 32; ++t) acc[t] = 0.f;
    const float* wrow = Wih0 + (size_t)r * (XDIM + EMBD);
    for (int k = 0; k < XDIM; ++k){
      float wv = wrow[k];
#pragma unroll
      for (int t = 0; t < 32; ++t) acc[t] += wv * xl[t * XDIM + k];
    }
    float bb = bih0[r] + bhh0[r];
    for (int t = 0; t < 32; ++t)
      PRE[(size_t)(tb * 32 + t) * 6144 + r] = acc[t] + bb;
  }
}

// Wc = W_out @ W_hl (128x1536, K=1024); bc = W_out @ b_hl + b_out
__global__ void k_wc(const float* Whl, const float* Wout, const float* bhl, const float* bout,
                     float* Wc, float* bc){
  if (blockIdx.x == 96){
    int j = threadIdx.x;
    if (j < 128){
      float a = 0.f;
      for (int m = 0; m < 1024; ++m) a += Wout[(size_t)j * 1024 + m] * bhl[m];
      bc[j] = a + bout[j];
    }
    return;
  }
  int kt = blockIdx.x % 6, jt = blockIdx.x / 6;
  __shared__ float wo[8 * 1024];
  int tid = threadIdx.x;
  for (int i = tid; i < 8 * 1024; i += 256) wo[i] = Wout[(size_t)(jt * 8) * 1024 + i];
  __syncthreads();
  int k = kt * 256 + tid;
  float acc[8];
#pragma unroll
  for (int jj = 0; jj < 8; ++jj) acc[jj] = 0.f;
  for (int m = 0; m < 1024; ++m){
    float wl = Whl[(size_t)m * HD + k];
#pragma unroll
    for (int jj = 0; jj < 8; ++jj) acc[jj] += wo[jj * 1024 + m] * wl;
  }
#pragma unroll
  for (int jj = 0; jj < 8; ++jj) Wc[(size_t)(jt * 8 + jj) * HD + k] = acc[jj];
}

__global__ void k_sentinel(float* out){ out[0] = 1.0e6f; }

extern "C" void kernel_launch(void* const* d_in, const int* in_sizes, int n_in,
                              void* d_out, int out_size, void* d_ws, size_t ws_size,
                              hipStream_t stream){
  (void)in_sizes; (void)n_in; (void)out_size;
  const float* x    = (const float*)d_in[0];
  const float* h0in = (const float*)d_in[1];
  const float* c0in = (const float*)d_in[2];
  const float* Wih0 = (const float*)d_in[3];
  const float* Whh0 = (const float*)d_in[4];
  const float* bih0 = (const float*)d_in[5];
  const float* bhh0 = (const float*)d_in[6];
  const float* Wih1 = (const float*)d_in[7];
  const float* Whh1 = (const float*)d_in[8];
  const float* bih1 = (const float*)d_in[9];
  const float* bhh1 = (const float*)d_in[10];
  const float* Whl  = (const float*)d_in[11];
  const float* bhl  = (const float*)d_in[12];
  const float* Wout = (const float*)d_in[13];
  const float* bout = (const float*)d_in[14];
  const float* Wmap = (const float*)d_in[15];
  const float* bmap = (const float*)d_in[16];
  float* out = (float*)d_out;
  float* ws = (float*)d_ws;

  size_t off = 0;
  float* PRE    = ws + off; off += (size_t)T_STEPS * 6144;
  float* Wc     = ws + off; off += 128 * HD;
  float* bc     = ws + off; off += 128;
  float* h0buf  = ws + off; off += 2 * HD;
  float* h1buf  = ws + off; off += 2 * HD;
  float* embbuf = ws + off; off += 2 * EMBD;
  float* PART   = ws + off; off += 128 * 128;
  off = (off + 63) & ~(size_t)63;
  uint32_t* ep  = (uint32_t*)(ws + off); off += EP_N;

  if (ws_size < off * sizeof(float) + 1024){
    hipLaunchKernelGGL(k_sentinel, dim3(1), dim3(1), 0, stream, out);
    return;
  }

  // opt-in to >64KB dynamic LDS (160 KiB/CU on gfx950); unconditional, idempotent
  (void)hipFuncSetAttribute(reinterpret_cast<const void*>(k_lstm),
                            hipFuncAttributeMaxDynamicSharedMemorySize, SMEM_BYTES);

  hipLaunchKernelGGL(k_init, dim3(1), dim3(256), 0, stream, h0in, h0buf, h1buf, embbuf, ep);
  hipLaunchKernelGGL(k_pre, dim3(256), dim3(256), 0, stream, x, Wih0, bih0, bhh0, PRE);
  hipLaunchKernelGGL(k_wc, dim3(97), dim3(256), 0, stream, Whl, Wout, bhl, bout, Wc, bc);

  Params P;
  P.x = x; P.h0in = h0in; P.c0in = c0in;
  P.Wih0 = Wih0; P.Whh0 = Whh0; P.bih0 = bih0; P.bhh0 = bhh0;
  P.Wih1 = Wih1; P.Whh1 = Whh1; P.bih1 = bih1; P.bhh1 = bhh1;
  P.Whl = Whl; P.bhl = bhl; P.Wout = Wout; P.bout = bout; P.Wmap = Wmap; P.bmap = bmap;
  P.PRE = PRE; P.Wc = Wc; P.bc = bc;
  P.h0buf = h0buf; P.h1buf = h1buf; P.embbuf = embbuf; P.PART = PART;
  P.ep = ep; P.out = out;

  hipLaunchKernelGGL(k_lstm, dim3(NBLK), dim3(1024), SMEM_BYTES, stream, P);
}